// Round 12
// baseline (336.175 us; speedup 1.0000x reference)
//
#include <hip/hip_runtime.h>

#define HID 128
#define BM 128
#define BN 128
#define BKS 32
#define ALD 36          // LDS row stride in shorts (72B: odd multiple of 8B -> uniform banks)
#define SCAN_BLK 256
#define SCAN_ELEMS 1024

typedef float v4f __attribute__((ext_vector_type(4)));
typedef short v4s __attribute__((ext_vector_type(4)));
typedef short v8s __attribute__((ext_vector_type(8)));

__device__ __forceinline__ void split_bf16(float v, unsigned short& hi, unsigned short& lo) {
  const unsigned int u = __float_as_uint(v);
  hi = (unsigned short)(u >> 16);
  const float rem = v - __uint_as_float(u & 0xffff0000u);  // exact
  lo = (unsigned short)(__float_as_uint(rem) >> 16);
}

// ---- compose transposed+split B: Bt[n][k], k in [0,KT) ----
__global__ void compose_Bt(const float* __restrict__ W_lin, const float* __restrict__ W_r,
                           unsigned short* __restrict__ Bth, unsigned short* __restrict__ Btl,
                           int KT) {
  const int k = blockIdx.x;
  const int n = threadIdx.x;
  float v;
  if (k < HID) {
    v = W_lin[n * (2 * HID) + k];
  } else {
    const int rr = (k - HID) >> 7;
    const int j  = (k - HID) & (HID - 1);
    const float* wl = W_lin + n * (2 * HID) + HID;
    const float* wr = W_r + (size_t)rr * HID * HID + j;
    float acc = 0.f;
#pragma unroll 8
    for (int i2 = 0; i2 < HID; ++i2)
      acc = fmaf(wl[i2], wr[i2 * HID], acc);
    v = acc;
  }
  unsigned short hi, lo;
  split_bf16(v, hi, lo);
  Bth[(size_t)n * KT + k] = hi;
  Btl[(size_t)n * KT + k] = lo;
}

// ---- counting sort by key = dst*NUM_R + rating ----
__global__ void hist_kernel(const int* __restrict__ ed, const int* __restrict__ er,
                            int* __restrict__ hist, int NE, int NUMR) {
  const int i = blockIdx.x * blockDim.x + threadIdx.x;
  if (i < NE) atomicAdd(hist + ed[i] * NUMR + er[i], 1);
}

__global__ __launch_bounds__(SCAN_BLK)
void scan_phaseA(const int* __restrict__ cnt, int* __restrict__ partials, int n) {
  __shared__ int red[SCAN_BLK];
  const int tid = threadIdx.x;
  const int base = blockIdx.x * SCAN_ELEMS + tid * 4;
  int s = 0;
#pragma unroll
  for (int j = 0; j < 4; ++j) {
    const int i = base + j;
    if (i < n) s += cnt[i];
  }
  red[tid] = s;
  __syncthreads();
  for (int off = SCAN_BLK / 2; off > 0; off >>= 1) {
    if (tid < off) red[tid] += red[tid + off];
    __syncthreads();
  }
  if (tid == 0) partials[blockIdx.x] = red[0];
}

__global__ __launch_bounds__(1024)
void scan_phaseB(int* __restrict__ partials, int* __restrict__ offs_n, int nb) {
  __shared__ int ps[1024];
  const int tid = threadIdx.x;
  const int chunk = (nb + 1023) / 1024;
  const int b0 = tid * chunk;
  const int e0 = min(b0 + chunk, nb);
  int s = 0;
  for (int i = b0; i < e0; ++i) s += partials[i];
  ps[tid] = s;
  __syncthreads();
  for (int off = 1; off < 1024; off <<= 1) {
    const int t = (tid >= off) ? ps[tid - off] : 0;
    __syncthreads();
    ps[tid] += t;
    __syncthreads();
  }
  int run = ps[tid] - s;
  for (int i = b0; i < e0; ++i) {
    const int c = partials[i];
    partials[i] = run;
    run += c;
  }
  if (tid == 1023) offs_n[0] = ps[1023];
}

__global__ __launch_bounds__(SCAN_BLK)
void scan_phaseC(const int* __restrict__ cnt, const int* __restrict__ partials,
                 int* __restrict__ offs, int* __restrict__ cursor, int n) {
  __shared__ int tsum[SCAN_BLK];
  const int tid = threadIdx.x;
  const int base = blockIdx.x * SCAN_ELEMS + tid * 4;
  int v[4];
  int s = 0;
#pragma unroll
  for (int j = 0; j < 4; ++j) {
    const int i = base + j;
    v[j] = (i < n) ? cnt[i] : 0;
    s += v[j];
  }
  tsum[tid] = s;
  __syncthreads();
  for (int off = 1; off < SCAN_BLK; off <<= 1) {
    const int t = (tid >= off) ? tsum[tid - off] : 0;
    __syncthreads();
    tsum[tid] += t;
    __syncthreads();
  }
  int run = partials[blockIdx.x] + tsum[tid] - s;
#pragma unroll
  for (int j = 0; j < 4; ++j) {
    const int i = base + j;
    if (i < n) {
      offs[i] = run;
      cursor[i] = run;
      run += v[j];
    }
  }
}

__global__ void reorder_kernel(const int* __restrict__ es, const int* __restrict__ ed,
                               const int* __restrict__ er, int* __restrict__ cursor,
                               int* __restrict__ sorted, int NE, int NUMR) {
  const int i = blockIdx.x * blockDim.x + threadIdx.x;
  if (i < NE) {
    const int key = ed[i] * NUMR + er[i];
    const int pos = atomicAdd(cursor + key, 1);
    sorted[pos] = es[i];
  }
}

// ---- aggregation: ONE WAVE PER DST; quarter-wave (4 edges in flight) ----
// lanes: quarter q = lane>>4 handles edges e = o0+q, o0+q+4, ...; 16 lanes x 8 floats/row
template <int NR>
__global__ __launch_bounds__(256)
void aggregate_dst(const float* __restrict__ src, const int* __restrict__ sorted,
                   const int* __restrict__ offs, float* __restrict__ S, int NDST) {
  const int d = (blockIdx.x * (blockDim.x >> 6)) + (threadIdx.x >> 6);
  if (d >= NDST) return;
  const int lane = threadIdx.x & 63;
  const int q = lane >> 4;          // 0..3
  const int c8 = (lane & 15) * 8;   // 0,8,...,120

  const int base = d * NR;
  const int o0 = offs[base];
  const int oN = offs[base + NR];
  int bnd[NR - 1];
#pragma unroll
  for (int r = 0; r < NR - 1; ++r) bnd[r] = offs[base + 1 + r];
  const float inv = 1.0f / fmaxf((float)(oN - o0), 1.0f);

  v4f a0[NR], a1[NR];
#pragma unroll
  for (int r = 0; r < NR; ++r) {
    a0[r] = (v4f){0.f, 0.f, 0.f, 0.f};
    a1[r] = (v4f){0.f, 0.f, 0.f, 0.f};
  }

  for (int e = o0 + q; e < oN; e += 4) {
    const int s = sorted[e];
    const float* sp = src + (size_t)s * HID + c8;
    const v4f v0 = *reinterpret_cast<const v4f*>(sp);
    const v4f v1 = *reinterpret_cast<const v4f*>(sp + 4);
    int rloc = 0;
#pragma unroll
    for (int r = 0; r < NR - 1; ++r) rloc += (e >= bnd[r]) ? 1 : 0;
#pragma unroll
    for (int r = 0; r < NR; ++r) {
      if (rloc == r) { a0[r] += v0; a1[r] += v1; }
    }
  }

  // combine quarters (xor 16, then xor 32), scale, NT store (lanes 0..15: 32B each)
#pragma unroll
  for (int r = 0; r < NR; ++r) {
    v4f t0 = a0[r], t1 = a1[r];
#pragma unroll
    for (int j = 0; j < 4; ++j) {
      t0[j] += __shfl_xor(t0[j], 16);
      t1[j] += __shfl_xor(t1[j], 16);
      t0[j] += __shfl_xor(t0[j], 32);
      t1[j] += __shfl_xor(t1[j], 32);
    }
    if (lane < 16) {
      t0 *= inv;
      t1 *= inv;
      float* op = S + (size_t)d * (NR * HID) + r * HID + c8;
      __builtin_nontemporal_store(t0, reinterpret_cast<v4f*>(op));
      __builtin_nontemporal_store(t1, reinterpret_cast<v4f*>(op + 4));
    }
  }
}

// generic fallback (one wave per segment), used only if NUM_R != 6
__global__ __launch_bounds__(256)
void aggregate_kernel(const float* __restrict__ src, const int* __restrict__ sorted,
                      const int* __restrict__ offs, float* __restrict__ S,
                      int NDST, int NUMR) {
  const int wid = (blockIdx.x * (blockDim.x >> 6)) + (threadIdx.x >> 6);
  const int lane = threadIdx.x & 63;
  if (wid >= NDST * NUMR) return;
  const int d = wid / NUMR;
  const int rloc = wid - d * NUMR;
  const int k = d * NUMR + rloc;
  const int o0 = offs[k], o1 = offs[k + 1];
  const int c0 = offs[d * NUMR], c1 = offs[d * NUMR + NUMR];
  const float inv = 1.0f / fmaxf((float)(c1 - c0), 1.0f);
  float ax = 0.f, ay = 0.f;
  for (int e = o0; e < o1; ++e) {
    const int s = sorted[e];
    const float2 v = *reinterpret_cast<const float2*>(src + (size_t)s * HID + lane * 2);
    ax += v.x; ay += v.y;
  }
  *reinterpret_cast<float2*>(S + (size_t)d * (NUMR * HID) + rloc * HID + lane * 2) =
      make_float2(ax * inv, ay * inv);
}

// ---- fused MFMA GEMM v4: 2-deep pipeline, double LDS buffer, 1 barrier/iter ----
struct Stage { v4f a0, a1; v8s bh, bl; };

__global__ __launch_bounds__(512)
void mfma_gemm(const float* __restrict__ dstf, const float* __restrict__ S,
               const unsigned short* __restrict__ Bth, const unsigned short* __restrict__ Btl,
               const float* __restrict__ b_lin, float* __restrict__ out,
               int M, int KT) {
  __shared__ unsigned short Ah[2][BM][ALD], Al[2][BM][ALD];
  __shared__ unsigned short Bh[2][BN][ALD], Bl[2][BN][ALD];

  const int tid = threadIdx.x;
  const int lane = tid & 63;
  const int wid = tid >> 6;
  const int wm = wid >> 1;        // 0..3 : 32-row band
  const int wn = wid & 1;         // 0..1 : 64-col band
  const int m0 = blockIdx.x * BM;
  const int l15 = lane & 15;
  const int kq = (lane >> 4) * 8;

  const int arow = tid >> 2;          // 0..127
  const int ac8 = (tid & 3) * 8;      // 0,8,16,24
  const int argr = m0 + arow;
  const int SSTRIDE = KT - HID;
  const int nkt = KT / BKS;           // 28 (even)

  v4f acc[2][4];
#pragma unroll
  for (int i = 0; i < 2; ++i)
#pragma unroll
    for (int j = 0; j < 4; ++j) acc[i][j] = (v4f){0.f, 0.f, 0.f, 0.f};

  auto loadTile = [&](int kg, Stage& st) {
    st.a0 = (v4f){0.f, 0.f, 0.f, 0.f};
    st.a1 = (v4f){0.f, 0.f, 0.f, 0.f};
    if (argr < M) {
      const float* p = (kg < HID)
          ? dstf + (size_t)argr * HID + kg + ac8
          : S + (size_t)argr * SSTRIDE + (kg - HID) + ac8;
      st.a0 = __builtin_nontemporal_load(reinterpret_cast<const v4f*>(p));
      st.a1 = __builtin_nontemporal_load(reinterpret_cast<const v4f*>(p + 4));
    }
    const size_t gb = (size_t)arow * KT + kg + ac8;
    st.bh = *reinterpret_cast<const v8s*>(Bth + gb);
    st.bl = *reinterpret_cast<const v8s*>(Btl + gb);
  };

  auto writeTile = [&](const Stage& st, int p) {
    union { v4s v[2]; unsigned short u[8]; } hh, ll;
#pragma unroll
    for (int j = 0; j < 4; ++j) split_bf16(st.a0[j], hh.u[j], ll.u[j]);
#pragma unroll
    for (int j = 0; j < 4; ++j) split_bf16(st.a1[j], hh.u[4 + j], ll.u[4 + j]);
    *reinterpret_cast<v4s*>(&Ah[p][arow][ac8])     = hh.v[0];
    *reinterpret_cast<v4s*>(&Ah[p][arow][ac8 + 4]) = hh.v[1];
    *reinterpret_cast<v4s*>(&Al[p][arow][ac8])     = ll.v[0];
    *reinterpret_cast<v4s*>(&Al[p][arow][ac8 + 4]) = ll.v[1];
    union { v8s v; v4s h[2]; } bu;
    bu.v = st.bh;
    *reinterpret_cast<v4s*>(&Bh[p][arow][ac8])     = bu.h[0];
    *reinterpret_cast<v4s*>(&Bh[p][arow][ac8 + 4]) = bu.h[1];
    bu.v = st.bl;
    *reinterpret_cast<v4s*>(&Bl[p][arow][ac8])     = bu.h[0];
    *reinterpret_cast<v4s*>(&Bl[p][arow][ac8 + 4]) = bu.h[1];
  };

  auto mfmaPhase = [&](int p) {
    union { v8s v; v4s h[2]; } afh[2], afl[2], bfh[4], bfl[4];
#pragma unroll
    for (int fm = 0; fm < 2; ++fm) {
      const int r = wm * 32 + fm * 16 + l15;
      afh[fm].h[0] = *reinterpret_cast<const v4s*>(&Ah[p][r][kq]);
      afh[fm].h[1] = *reinterpret_cast<const v4s*>(&Ah[p][r][kq + 4]);
      afl[fm].h[0] = *reinterpret_cast<const v4s*>(&Al[p][r][kq]);
      afl[fm].h[1] = *reinterpret_cast<const v4s*>(&Al[p][r][kq + 4]);
    }
#pragma unroll
    for (int fn = 0; fn < 4; ++fn) {
      const int c = wn * 64 + fn * 16 + l15;
      bfh[fn].h[0] = *reinterpret_cast<const v4s*>(&Bh[p][c][kq]);
      bfh[fn].h[1] = *reinterpret_cast<const v4s*>(&Bh[p][c][kq + 4]);
      bfl[fn].h[0] = *reinterpret_cast<const v4s*>(&Bl[p][c][kq]);
      bfl[fn].h[1] = *reinterpret_cast<const v4s*>(&Bl[p][c][kq + 4]);
    }
#pragma unroll
    for (int fm = 0; fm < 2; ++fm)
#pragma unroll
      for (int fn = 0; fn < 4; ++fn) {
        acc[fm][fn] = __builtin_amdgcn_mfma_f32_16x16x32_bf16(afh[fm].v, bfh[fn].v, acc[fm][fn], 0, 0, 0);
        acc[fm][fn] = __builtin_amdgcn_mfma_f32_16x16x32_bf16(afh[fm].v, bfl[fn].v, acc[fm][fn], 0, 0, 0);
        acc[fm][fn] = __builtin_amdgcn_mfma_f32_16x16x32_bf16(afl[fm].v, bfh[fn].v, acc[fm][fn], 0, 0, 0);
      }
  };

  // prologue: tile0 -> buf0 (waits its own loads); tile1 loads left in flight in SB
  Stage SA, SB;
  loadTile(0, SA);
  writeTile(SA, 0);
  loadTile(BKS, SB);
  __syncthreads();

  // steady state: tile kt lives in buf[kt&1]; loads issued ~1.7 iters before LDS write
  for (int kt = 0; kt < nkt; kt += 2) {
    // even sub-iter: consume buf0 (tile kt); SB holds tile kt+1 in flight
    if (kt + 2 < nkt) loadTile((kt + 2) * BKS, SA);
    mfmaPhase(0);
    if (kt + 1 < nkt) writeTile(SB, 1);
    __syncthreads();
    if (kt + 1 >= nkt) break;
    // odd sub-iter: consume buf1 (tile kt+1); SA holds tile kt+2 in flight
    if (kt + 3 < nkt) loadTile((kt + 3) * BKS, SB);
    mfmaPhase(1);
    if (kt + 2 < nkt) writeTile(SA, 0);
    __syncthreads();
  }

  // epilogue: bias + relu; C/D map: col=lane&15, row=(lane>>4)*4+reg
#pragma unroll
  for (int fn = 0; fn < 4; ++fn) {
    const int cn = wn * 64 + fn * 16 + l15;
    const float bias = b_lin[cn];
#pragma unroll
    for (int fm = 0; fm < 2; ++fm) {
      const int row0 = m0 + wm * 32 + fm * 16 + (lane >> 4) * 4;
#pragma unroll
      for (int r = 0; r < 4; ++r) {
        const int rg = row0 + r;
        if (rg < M) out[(size_t)rg * HID + cn] = fmaxf(acc[fm][fn][r] + bias, 0.f);
      }
    }
  }
}

extern "C" void kernel_launch(void* const* d_in, const int* in_sizes, int n_in,
                              void* d_out, int out_size, void* d_ws, size_t ws_size,
                              hipStream_t stream) {
  const float* src   = (const float*)d_in[0];
  const float* dstf  = (const float*)d_in[1];
  const float* W_r   = (const float*)d_in[2];
  const float* W_lin = (const float*)d_in[3];
  const float* b_lin = (const float*)d_in[4];
  const int* e_src   = (const int*)d_in[5];
  const int* e_dst   = (const int*)d_in[6];
  const int* e_rat   = (const int*)d_in[7];

  const int N_DST = in_sizes[1] / HID;
  const int NUM_R = in_sizes[2] / (HID * HID);
  const int NE = in_sizes[5];
  const int KT = HID + NUM_R * HID;     // 896
  const int NKEY = N_DST * NUM_R;       // 300000
  const int NB = (NKEY + SCAN_ELEMS - 1) / SCAN_ELEMS;

  const size_t S_b      = (size_t)N_DST * (NUM_R * HID) * sizeof(float);  // 153.6 MB
  const size_t hist_b   = (size_t)NKEY * sizeof(int);
  const size_t offs_b   = (size_t)(NKEY + 1) * sizeof(int);
  const size_t cursor_b = (size_t)NKEY * sizeof(int);
  const size_t sorted_b = (size_t)NE * sizeof(int);
  const size_t part_b   = (size_t)NB * sizeof(int);
  const size_t Bt_b     = (size_t)HID * KT * sizeof(unsigned short);
  const size_t need = S_b + hist_b + offs_b + cursor_b + sorted_b + part_b + 2 * Bt_b + 4096;
  if (ws_size < need) return;  // fail loudly in verification

  char* p = (char*)d_ws;
  float* S = (float*)p;            p += (S_b + 255) & ~(size_t)255;
  int* hist = (int*)p;             p += (hist_b + 255) & ~(size_t)255;
  int* offs = (int*)p;             p += (offs_b + 255) & ~(size_t)255;
  int* cursor = (int*)p;           p += (cursor_b + 255) & ~(size_t)255;
  int* sorted = (int*)p;           p += (sorted_b + 255) & ~(size_t)255;
  int* partials = (int*)p;         p += (part_b + 255) & ~(size_t)255;
  unsigned short* Bth = (unsigned short*)p;  p += (Bt_b + 255) & ~(size_t)255;
  unsigned short* Btl = (unsigned short*)p;

  compose_Bt<<<KT, HID, 0, stream>>>(W_lin, W_r, Bth, Btl, KT);
  hipMemsetAsync(hist, 0, hist_b, stream);
  hist_kernel<<<(NE + 255) / 256, 256, 0, stream>>>(e_dst, e_rat, hist, NE, NUM_R);
  scan_phaseA<<<NB, SCAN_BLK, 0, stream>>>(hist, partials, NKEY);
  scan_phaseB<<<1, 1024, 0, stream>>>(partials, offs + NKEY, NB);
  scan_phaseC<<<NB, SCAN_BLK, 0, stream>>>(hist, partials, offs, cursor, NKEY);
  reorder_kernel<<<(NE + 255) / 256, 256, 0, stream>>>(e_src, e_dst, e_rat, cursor,
                                                       sorted, NE, NUM_R);
  if (NUM_R == 6) {
    aggregate_dst<6><<<(N_DST + 3) / 4, 256, 0, stream>>>(src, sorted, offs, S, N_DST);
  } else {
    const int nwaves = N_DST * NUM_R;
    aggregate_kernel<<<(nwaves + 3) / 4, 256, 0, stream>>>(src, sorted, offs, S,
                                                           N_DST, NUM_R);
  }
  const int mb = (N_DST + BM - 1) / BM;
  mfma_gemm<<<mb, 512, 0, stream>>>(dstf, S, Bth, Btl, b_lin, (float*)d_out,
                                    N_DST, KT);
}